// Round 12
// baseline (381.034 us; speedup 1.0000x reference)
//
#include <hip/hip_runtime.h>

#define N_NODES 50000
#define N_EDGES 800000
#define DIN 384
#define DH 128
#define NB 64
#define NEG 0.2f

// ---------------- bf16 helpers (exact bit ops) ----------------
__device__ __forceinline__ float bf2f(unsigned short u) {
    return __uint_as_float((unsigned)u << 16);
}
__device__ __forceinline__ unsigned short f2bf(float x) {  // RNE
    unsigned u = __float_as_uint(x);
    return (unsigned short)((u + 0x7fff + ((u >> 16) & 1)) >> 16);
}
__device__ __forceinline__ float sel4(float4 v, int k) {
    float r = v.x;
    r = (k == 1) ? v.y : r;
    r = (k == 2) ? v.z : r;
    r = (k == 3) ? v.w : r;
    return r;
}
using us8 = __attribute__((ext_vector_type(8))) unsigned short;
using short8 = __attribute__((ext_vector_type(8))) short;
using f32x4  = __attribute__((ext_vector_type(4))) float;

// ---------------- fused proj GEMM ∥ (histogram + ew-sum) --------------------
// Blocks 0..781: projection GEMM (BM=64). B staged with COALESCED float4 reads
// of Wp rows + transposed bf16 LDS writes (R11 lesson: the stride-512B scalar
// W loads + weight-prep branch pushed VGPR to 80 / occupancy to 25%).
// Blocks 782..1805: edge histogram grid-stride (weight prep moved to scan_a).
#define PROJB 782
#define HISTB 1024
__global__ __launch_bounds__(256) void histproj_kernel(
    // hist args
    const int* __restrict__ dst, const float* __restrict__ ew,
    int* __restrict__ cnt, int* __restrict__ rank, float* __restrict__ ews,
    // proj args
    const float* __restrict__ A, const float* __restrict__ Wp,
    const float* __restrict__ bias, float* __restrict__ C,
    unsigned short* __restrict__ Cb, int M)
{
    const int tid = threadIdx.x;

    if (blockIdx.x >= PROJB) {
        // ---------------- hist ----------------
        __shared__ float sred[4];
        const int hb = blockIdx.x - PROJB;   // 0..1023
        float v = 0.0f;
        for (int i = hb * 256 + tid; i < N_EDGES; i += HISTB * 256) {
            rank[i] = atomicAdd(&cnt[dst[i]], 1);
            v += ew[i];
        }
        #pragma unroll
        for (int o = 32; o; o >>= 1) v += __shfl_down(v, o, 64);
        if ((tid & 63) == 0) sred[tid >> 6] = v;
        __syncthreads();
        if (tid == 0) atomicAdd(ews, sred[0] + sred[1] + sred[2] + sred[3]);
        return;
    }

    // ---------------- projection GEMM (BM=64) ----------------
    constexpr int K = DIN, BM = 64, BK = 32, LS = 40;
    __shared__ unsigned short As[BM * LS];   // 5.1 KB
    __shared__ unsigned short Bs[DH * LS];   // 10.2 KB

    const int w = tid >> 6, l = tid & 63;
    const int lane16 = l & 15, quad = l >> 4;
    const int m0 = blockIdx.x * BM;

    f32x4 acc[8] = {};

    const int ar = tid >> 2, a4 = tid & 3;   // 64 rows x 4 quarters
    int arow = m0 + ar; if (arow >= M) arow = M - 1;
    const float* Ap = A + (size_t)arow * K;

    for (int k0 = 0; k0 < K; k0 += BK) {
        __syncthreads();
        #pragma unroll
        for (int i = 0; i < 2; ++i) {
            const int f4 = a4 + 4 * i;
            float4 v = *(const float4*)(Ap + k0 + f4 * 4);
            ushort4 u = {f2bf(v.x), f2bf(v.y), f2bf(v.z), f2bf(v.w)};
            *(ushort4*)&As[ar * LS + f4 * 4] = u;
        }
        // coalesced W staging: thread reads float4 of row k (contiguous n),
        // writes 4 bf16 to transposed LDS (2-way bank alias = free).
        #pragma unroll
        for (int rep = 0; rep < 4; ++rep) {
            const int lin = rep * 256 + tid;       // 0..1023
            const int kk = lin >> 5;               // 0..31
            const int n0 = (lin & 31) * 4;         // 0..124
            float4 v = *(const float4*)(Wp + (size_t)(k0 + kk) * DH + n0);
            Bs[(n0 + 0) * LS + kk] = f2bf(v.x);
            Bs[(n0 + 1) * LS + kk] = f2bf(v.y);
            Bs[(n0 + 2) * LS + kk] = f2bf(v.z);
            Bs[(n0 + 3) * LS + kk] = f2bf(v.w);
        }
        __syncthreads();
        short8 afr = *(short8*)&As[(w * 16 + lane16) * LS + quad * 8];
        #pragma unroll
        for (int nt = 0; nt < 8; ++nt) {
            short8 bf = *(short8*)&Bs[(nt * 16 + lane16) * LS + quad * 8];
            acc[nt] = __builtin_amdgcn_mfma_f32_16x16x32_bf16(afr, bf, acc[nt], 0, 0, 0);
        }
    }

    const int orow0 = m0 + w * 16 + quad * 4;
    #pragma unroll
    for (int nt = 0; nt < 8; ++nt) {
        const int col = nt * 16 + lane16;
        const float bv = bias[col];
        #pragma unroll
        for (int r = 0; r < 4; ++r) {
            const int row = orow0 + r;
            if (row < M) {
                const float v = acc[nt][r] + bv;
                C[(size_t)row * DH + col] = v;
                Cb[(size_t)row * DH + col] = f2bf(v);
            }
        }
    }
}

// ---------------- scan stage A (+ consts + layer-weight prep) ---------------
// Blocks 0..SB-1: per-block exclusive scan. Block SB: edge-attn consts.
// Blocks SB+1..SB+64: W0/W1 -> Wt0/Wt1 bf16 transpose. SB+65..SB+68: folded
// logit columns (rows 128..135 of Wt). All ready before gemmfill-0.
#define SB 196
__global__ __launch_bounds__(256) void scan_a(const int* __restrict__ cnt,
                       int* __restrict__ scanned, int* __restrict__ bsums,
                       const float* __restrict__ We0, const float* __restrict__ ae0,
                       const float* __restrict__ We1, const float* __restrict__ ae1,
                       const float* __restrict__ ews, float* __restrict__ consts,
                       const float* __restrict__ W0, const float* __restrict__ W1,
                       const float* __restrict__ as0, const float* __restrict__ ad0,
                       const float* __restrict__ as1, const float* __restrict__ ad1,
                       unsigned short* __restrict__ Wt0, unsigned short* __restrict__ Wt1) {
    __shared__ int s[256];
    const int tid = threadIdx.x;
    if (blockIdx.x < SB) {
        int i = blockIdx.x * 256 + tid;
        int v = (i < N_NODES) ? cnt[i] : 0;
        s[tid] = v; __syncthreads();
        for (int o = 1; o < 256; o <<= 1) {
            int t = (tid >= o) ? s[tid - o] : 0;
            __syncthreads();
            s[tid] += t;
            __syncthreads();
        }
        if (i < N_NODES) scanned[i] = s[tid] - v;  // exclusive
        if (tid == 255) bsums[blockIdx.x] = s[255];
    } else if (blockIdx.x == SB) {
        if (tid < 64) {
            const int l = tid;
            float p00 = We0[l] * ae0[l];
            float p01 = We0[l + 64] * ae0[l + 64];
            float p10 = We1[l] * ae1[l];
            float p11 = We1[l + 64] * ae1[l + 64];
            #pragma unroll
            for (int o = 1; o < 32; o <<= 1) {
                p00 += __shfl_xor(p00, o, 64); p01 += __shfl_xor(p01, o, 64);
                p10 += __shfl_xor(p10, o, 64); p11 += __shfl_xor(p11, o, 64);
            }
            const float c0 = __shfl(p00, 0, 64), c1 = __shfl(p00, 32, 64);
            const float c2 = __shfl(p01, 0, 64), c3 = __shfl(p01, 32, 64);
            const float d0 = __shfl(p10, 0, 64), d1 = __shfl(p10, 32, 64);
            const float d2 = __shfl(p11, 0, 64), d3 = __shfl(p11, 32, 64);
            if (l == 0) {
                consts[0] = c0; consts[1] = c1; consts[2] = c2; consts[3] = c3;
                consts[4] = d0; consts[5] = d1; consts[6] = d2; consts[7] = d3;
                consts[8] = ews[0] * (1.0f / N_EDGES);
            }
        }
    } else if (blockIdx.x <= SB + 64) {
        const int pi = (blockIdx.x - SB - 1) * 256 + tid;  // 0..16383 = DH*DH
        const int k = pi >> 7, n = pi & 127;
        Wt0[(size_t)n * DH + k] = f2bf(W0[pi]);
        Wt1[(size_t)n * DH + k] = f2bf(W1[pi]);
    } else {
        const int b = blockIdx.x - SB - 65;   // 0..3 -> (layer, src/dst)
        const int layer = b >> 1, sd = b & 1;
        const float* Ws = layer ? W1 : W0;
        const float* av = layer ? (sd ? ad1 : as1) : (sd ? ad0 : as0);
        unsigned short* Wt = layer ? Wt1 : Wt0;
        #pragma unroll
        for (int rep = 0; rep < 2; ++rep) {
            const int idx = rep * 256 + tid;   // 0..511 -> (k, hd)
            const int k = idx >> 2, hd = idx & 3;
            float sacc = 0.f;
            for (int f = 0; f < 32; ++f)
                sacc += Ws[k * DH + hd * 32 + f] * av[hd * 32 + f];
            Wt[(size_t)(128 + sd * 4 + hd) * DH + k] = f2bf(sacc);
        }
    }
}

// ---------------- scan stage BC ----------------
__global__ __launch_bounds__(256) void scan_bc(const int* __restrict__ scanned,
                        const int* __restrict__ bsums,
                        const int* __restrict__ cnt, int* __restrict__ ptr) {
    __shared__ int red[4];
    const int tid = threadIdx.x;
    int part = 0;
    for (int j = tid; j < blockIdx.x; j += 256) part += bsums[j];
    #pragma unroll
    for (int o = 32; o; o >>= 1) part += __shfl_down(part, o, 64);
    if ((tid & 63) == 0) red[tid >> 6] = part;
    __syncthreads();
    const int off = red[0] + red[1] + red[2] + red[3];
    const int i = blockIdx.x * 256 + tid;
    if (i < N_NODES) {
        const int p = scanned[i] + off;
        ptr[i] = p;
        if (i == N_NODES - 1) ptr[N_NODES] = p + cnt[i];
    }
}

// ---------------- layer GEMM ∥ fill (layer 0 only) --------------------------
#define GEMMB 782
__global__ __launch_bounds__(256) void gemmfill_kernel(
    const unsigned short* __restrict__ Ab, const unsigned short* __restrict__ Wt,
    unsigned short* __restrict__ Hout, int M,
    float* __restrict__ asrc_o, float* __restrict__ adst_o,
    // fill args
    const int* __restrict__ src, const int* __restrict__ dst,
    const float* __restrict__ ew, const int* __restrict__ rank,
    const int* __restrict__ ptr, int2* __restrict__ recE)
{
    constexpr int K = DH, BM = 64, BK = 32, LS = 40;
    __shared__ unsigned short As[BM * LS];
    __shared__ unsigned short Bs[144 * LS];
    const int tid = threadIdx.x;

    if (blockIdx.x >= GEMMB) {
        const int e0 = ((blockIdx.x - GEMMB) * 256 + tid) * 4;
        if (e0 >= N_EDGES) return;
        const int4 d4 = *(const int4*)(dst + e0);
        const int4 s4 = *(const int4*)(src + e0);
        const int4 r4 = *(const int4*)(rank + e0);
        const float4 w4 = *(const float4*)(ew + e0);
        recE[ptr[d4.x] + r4.x] = make_int2(s4.x, __float_as_int(w4.x));
        recE[ptr[d4.y] + r4.y] = make_int2(s4.y, __float_as_int(w4.y));
        recE[ptr[d4.z] + r4.z] = make_int2(s4.z, __float_as_int(w4.z));
        recE[ptr[d4.w] + r4.w] = make_int2(s4.w, __float_as_int(w4.w));
        return;
    }

    const int w = tid >> 6, l = tid & 63;
    const int lane16 = l & 15, quad = l >> 4;
    const int m0 = blockIdx.x * BM;

    f32x4 acc[9] = {};

    const int ar = tid >> 2, aseg = tid & 3;
    int arow = m0 + ar; if (arow >= M) arow = M - 1;
    const unsigned short* Ap = Ab + (size_t)arow * K;

    for (int k0 = 0; k0 < K; k0 += BK) {
        __syncthreads();
        {
            us8 v = *(const us8*)(Ap + k0 + aseg * 8);
            *(us8*)&As[ar * LS + aseg * 8] = v;
        }
        #pragma unroll
        for (int i = 0; i < 3; ++i) {
            const int idx = tid + 256 * i;
            if (idx < 576) {
                const int bn = idx >> 2, seg = idx & 3;
                us8 v = *(const us8*)(Wt + (size_t)bn * K + k0 + seg * 8);
                *(us8*)&Bs[bn * LS + seg * 8] = v;
            }
        }
        __syncthreads();
        short8 af = *(short8*)&As[(w * 16 + lane16) * LS + quad * 8];
        #pragma unroll
        for (int nt = 0; nt < 9; ++nt) {
            short8 bf = *(short8*)&Bs[(nt * 16 + lane16) * LS + quad * 8];
            acc[nt] = __builtin_amdgcn_mfma_f32_16x16x32_bf16(af, bf, acc[nt], 0, 0, 0);
        }
    }

    const int orow0 = m0 + w * 16 + quad * 4;
    #pragma unroll
    for (int nt = 0; nt < 8; ++nt) {
        const int col = nt * 16 + lane16;
        #pragma unroll
        for (int r = 0; r < 4; ++r) {
            const int row = orow0 + r;
            if (row < M)
                Hout[(size_t)row * DH + col] = f2bf(acc[nt][r]);
        }
    }
    // logits from the 9th tile: cols 0..3 -> asrc, 4..7 -> adst
    #pragma unroll
    for (int r = 0; r < 4; ++r) {
        const int row = orow0 + r;
        if (row < M && lane16 < 8) {
            if (lane16 < 4) asrc_o[(size_t)row * 4 + lane16] = acc[8][r];
            else            adst_o[(size_t)row * 4 + (lane16 - 4)] = acc[8][r];
        }
    }
}

// ---------------- msg node compute (R5 4-edge version; R8 8-edge regressed) --
__device__ __forceinline__ void msg_node(
    const int n, const int c8, const int hd8,
    const float cc_l, const float ewm,
    const unsigned short* __restrict__ h,
    const float* __restrict__ asrc, const float* __restrict__ adst,
    const float* __restrict__ xres,
    const int* __restrict__ indptr, const int2* __restrict__ recE,
    const float* __restrict__ bias, const float* __restrict__ gamma,
    const float* __restrict__ beta, float z[8])
{
    const unsigned short* hb = h + c8 * 8;
    const int st = indptr[n];
    const int deg = indptr[n + 1] - st;
    const float ad_l = adst[(size_t)n * 4 + hd8];
    const float as_l = asrc[(size_t)n * 4 + hd8];

    // self-loop coefficient (|alpha| << 1 -> exp without max-shift is exact softmax)
    float a0 = as_l + ad_l + ewm * cc_l;
    a0 = a0 > 0.f ? a0 : NEG * a0;
    const float pv0_l = __expf(a0);

    float dsum = 0.f;
    float acc8[8];
    {
        us8 u = *(const us8*)(hb + (size_t)n * DH);
        #pragma unroll
        for (int i = 0; i < 8; ++i) acc8[i] = pv0_l * bf2f(u[i]);
    }

    const int2* rq = recE + st;
    int e = 0;
    for (; e + 3 < deg; e += 4) {
        const int2 r0 = rq[e],     r1 = rq[e + 1];
        const int2 r2 = rq[e + 2], r3 = rq[e + 3];
        const float av0 = asrc[(size_t)r0.x * 4 + hd8];
        const float av1 = asrc[(size_t)r1.x * 4 + hd8];
        const float av2 = asrc[(size_t)r2.x * 4 + hd8];
        const float av3 = asrc[(size_t)r3.x * 4 + hd8];
        us8 u0 = *(const us8*)(hb + (size_t)r0.x * DH);
        us8 u1 = *(const us8*)(hb + (size_t)r1.x * DH);
        us8 u2 = *(const us8*)(hb + (size_t)r2.x * DH);
        us8 u3 = *(const us8*)(hb + (size_t)r3.x * DH);
        float al0 = av0 + ad_l + __int_as_float(r0.y) * cc_l;
        float al1 = av1 + ad_l + __int_as_float(r1.y) * cc_l;
        float al2 = av2 + ad_l + __int_as_float(r2.y) * cc_l;
        float al3 = av3 + ad_l + __int_as_float(r3.y) * cc_l;
        al0 = al0 > 0.f ? al0 : NEG * al0;
        al1 = al1 > 0.f ? al1 : NEG * al1;
        al2 = al2 > 0.f ? al2 : NEG * al2;
        al3 = al3 > 0.f ? al3 : NEG * al3;
        const float c0 = __expf(al0), c1 = __expf(al1);
        const float c2 = __expf(al2), c3 = __expf(al3);
        dsum += (c0 + c1) + (c2 + c3);
        #pragma unroll
        for (int i = 0; i < 8; ++i)
            acc8[i] = fmaf(c0, bf2f(u0[i]),
                      fmaf(c1, bf2f(u1[i]),
                      fmaf(c2, bf2f(u2[i]),
                      fmaf(c3, bf2f(u3[i]), acc8[i]))));
    }
    for (; e < deg; ++e) {
        const int2 r = rq[e];
        const float av = asrc[(size_t)r.x * 4 + hd8];
        us8 u = *(const us8*)(hb + (size_t)r.x * DH);
        float al = av + ad_l + __int_as_float(r.y) * cc_l;
        al = al > 0.f ? al : NEG * al;
        const float c = __expf(al);
        dsum += c;
        #pragma unroll
        for (int i = 0; i < 8; ++i) acc8[i] = fmaf(c, bf2f(u[i]), acc8[i]);
    }

    const float inv_d = 1.0f / (dsum + pv0_l + 1e-16f);
    const float4 b4a = *(const float4*)(bias + c8 * 8);
    const float4 b4b = *(const float4*)(bias + c8 * 8 + 4);
    float y[8];
    y[0] = acc8[0] * inv_d + b4a.x; y[1] = acc8[1] * inv_d + b4a.y;
    y[2] = acc8[2] * inv_d + b4a.z; y[3] = acc8[3] * inv_d + b4a.w;
    y[4] = acc8[4] * inv_d + b4b.x; y[5] = acc8[5] * inv_d + b4b.y;
    y[6] = acc8[6] * inv_d + b4b.z; y[7] = acc8[7] * inv_d + b4b.w;

    float s1 = 0.f, s2 = 0.f;
    #pragma unroll
    for (int i = 0; i < 8; ++i) { s1 += y[i]; s2 += y[i] * y[i]; }
    #pragma unroll
    for (int o = 1; o < 16; o <<= 1) {   // stays within the 16-lane group
        s1 += __shfl_xor(s1, o, 64);
        s2 += __shfl_xor(s2, o, 64);
    }
    const float mu = s1 * (1.0f / DH);
    const float var = s2 * (1.0f / DH) - mu * mu;
    const float rs = rsqrtf(var + 1e-5f);

    const float4 g4a = *(const float4*)(gamma + c8 * 8);
    const float4 g4b = *(const float4*)(gamma + c8 * 8 + 4);
    const float4 e4a = *(const float4*)(beta + c8 * 8);
    const float4 e4b = *(const float4*)(beta + c8 * 8 + 4);
    const float4 r4a = *(const float4*)(xres + (size_t)n * DH + c8 * 8);
    const float4 r4b = *(const float4*)(xres + (size_t)n * DH + c8 * 8 + 4);
    const float gv[8] = {g4a.x, g4a.y, g4a.z, g4a.w, g4b.x, g4b.y, g4b.z, g4b.w};
    const float ev[8] = {e4a.x, e4a.y, e4a.z, e4a.w, e4b.x, e4b.y, e4b.z, e4b.w};
    const float rv[8] = {r4a.x, r4a.y, r4a.z, r4a.w, r4b.x, r4b.y, r4b.z, r4b.w};
    #pragma unroll
    for (int i = 0; i < 8; ++i) {
        float t = (y[i] - mu) * rs * gv[i] + ev[i];
        z[i] = (t > 0.f ? t : __expf(t) - 1.0f) + rv[i];
    }
}

// ---------------- msg: full TLP, both layers (pool un-fused per ledger) -----
#define MSG_NPB 16
__global__ __launch_bounds__(256) void msg_main_kernel(
    const unsigned short* __restrict__ h, const float* __restrict__ asrc,
    const float* __restrict__ adst, const float* __restrict__ xres,
    const int* __restrict__ indptr, const int2* __restrict__ recE,
    const float* __restrict__ consts, const int layer,
    const float* __restrict__ bias, const float* __restrict__ gamma,
    const float* __restrict__ beta, float* __restrict__ xout,
    unsigned short* __restrict__ xob)
{
    const int l = threadIdx.x & 63;
    const int wv = threadIdx.x >> 6;
    const int grp = l >> 4, c8 = l & 15, hd8 = c8 >> 2;
    const int n = blockIdx.x * MSG_NPB + wv * 4 + grp;  // exact: 3125*16=50000

    const float cc_l = sel4(*(const float4*)(consts + layer * 4), hd8);
    const float ewm = consts[8];

    float z[8];
    msg_node(n, c8, hd8, cc_l, ewm, h, asrc, adst, xres, indptr, recE,
             bias, gamma, beta, z);

    *(float4*)(xout + (size_t)n * DH + c8 * 8)     = *(float4*)&z[0];
    *(float4*)(xout + (size_t)n * DH + c8 * 8 + 4) = *(float4*)&z[4];
    if (xob) {
        ushort4 ub0 = {f2bf(z[0]), f2bf(z[1]), f2bf(z[2]), f2bf(z[3])};
        ushort4 ub1 = {f2bf(z[4]), f2bf(z[5]), f2bf(z[6]), f2bf(z[7])};
        *(ushort4*)(xob + (size_t)n * DH + c8 * 8)     = ub0;
        *(ushort4*)(xob + (size_t)n * DH + c8 * 8 + 4) = ub1;
    }
}

// ---------------- global mean pool (R3 measured-good structure) -------------
#define PNODES 64
__global__ __launch_bounds__(128) void pool_kernel(const float* __restrict__ x,
        const int* __restrict__ batch, float* __restrict__ pool, int* __restrict__ gcnt)
{
    int t = threadIdx.x;
    int n0 = blockIdx.x * PNODES;
    if (n0 >= N_NODES) return;
    int n1 = min(n0 + PNODES, N_NODES);
    float acc = 0.f; int cn = 0;
    int curb = batch[n0];
    for (int n = n0; n < n1; ++n) {
        int b = batch[n];
        if (b != curb) {
            atomicAdd(&pool[(size_t)curb * DH + t], acc);
            if (t == 0) atomicAdd(&gcnt[curb], cn);
            acc = 0.f; cn = 0; curb = b;
        }
        acc += x[(size_t)n * DH + t];
        ++cn;
    }
    atomicAdd(&pool[(size_t)curb * DH + t], acc);
    if (t == 0) atomicAdd(&gcnt[curb], cn);
}

__global__ void div_kernel(const float* __restrict__ pool, const int* __restrict__ gcnt,
                           float* __restrict__ out)
{
    int i = blockIdx.x * blockDim.x + threadIdx.x;
    if (i < NB * DH) {
        float c = (float)gcnt[i >> 7];
        out[i] = pool[i] / fmaxf(c, 1.0f);
    }
}

// ---------------- launch ----------------
extern "C" void kernel_launch(void* const* d_in, const int* in_sizes, int n_in,
                              void* d_out, int out_size, void* d_ws, size_t ws_size,
                              hipStream_t stream)
{
    const float* nf    = (const float*)d_in[0];
    const int*   esrc  = (const int*)d_in[1];
    const int*   edst  = esrc + N_EDGES;
    const float* ew    = (const float*)d_in[2];
    const int*   batch = (const int*)d_in[3];
    const float* Wp    = (const float*)d_in[4];
    const float* bp    = (const float*)d_in[5];
    const float* Wl[2]  = {(const float*)d_in[6],  (const float*)d_in[14]};
    const float* asl[2] = {(const float*)d_in[7],  (const float*)d_in[15]};
    const float* adl[2] = {(const float*)d_in[8],  (const float*)d_in[16]};
    const float* Wel[2] = {(const float*)d_in[9],  (const float*)d_in[17]};
    const float* ael[2] = {(const float*)d_in[10], (const float*)d_in[18]};
    const float* bl[2]  = {(const float*)d_in[11], (const float*)d_in[19]};
    const float* gl[2]  = {(const float*)d_in[12], (const float*)d_in[20]};
    const float* bel[2] = {(const float*)d_in[13], (const float*)d_in[21]};
    float* outp = (float*)d_out;

    char* w = (char*)d_ws;
    auto alloc = [&](size_t bytes) { char* p = w; w += (bytes + 255) & ~255ull; return p; };
    float* xA     = (float*)alloc((size_t)N_NODES * DH * 4);
    float* xB     = (float*)alloc((size_t)N_NODES * DH * 4);
    unsigned short* hbuf = (unsigned short*)alloc((size_t)N_NODES * DH * 2);
    unsigned short* xb   = (unsigned short*)alloc((size_t)N_NODES * DH * 2);
    float* asrc   = (float*)alloc((size_t)N_NODES * 4 * 4);
    float* adst   = (float*)alloc((size_t)N_NODES * 4 * 4);
    // contiguous zero-init group: pool | gcnt | ews | cnt  (one memset)
    float* pool   = (float*)alloc((size_t)NB * DH * 4);
    int* gcnt     = (int*)alloc(256);
    float* ews    = (float*)alloc(256);
    int* cnt      = (int*)alloc((size_t)N_NODES * 4);
    int* scanned  = (int*)alloc((size_t)N_NODES * 4);
    int* bsums    = (int*)alloc(1024);
    int* ptr      = (int*)alloc((size_t)(N_NODES + 8) * 4);
    int* rank     = (int*)alloc((size_t)N_EDGES * 4);
    int2* recE    = (int2*)alloc((size_t)N_EDGES * 8);
    float* consts = (float*)alloc(256);
    unsigned short* Wt0 = (unsigned short*)alloc((size_t)144 * DH * 2);
    unsigned short* Wt1 = (unsigned short*)alloc((size_t)144 * DH * 2);
    unsigned short* Wts[2] = {Wt0, Wt1};

    hipMemsetAsync(pool, 0, (size_t)NB * DH * 4 + 256 + 256 + (size_t)N_NODES * 4, stream);

    // stage 1: proj GEMM ∥ histogram/ew-sum
    histproj_kernel<<<PROJB + HISTB, 256, 0, stream>>>(
        edst, ew, cnt, rank, ews,
        nf, Wp, bp, xA, xb, N_NODES);

    // stage 2: scan + consts + layer-weight prep (spare blocks)
    scan_a<<<SB + 69, 256, 0, stream>>>(cnt, scanned, bsums,
                                        Wel[0], ael[0], Wel[1], ael[1], ews, consts,
                                        Wl[0], Wl[1], asl[0], adl[0], asl[1], adl[1],
                                        Wt0, Wt1);
    scan_bc<<<SB, 256, 0, stream>>>(scanned, bsums, cnt, ptr);

    const int mb = N_NODES / MSG_NPB;    // 3125

    // layer 0: gemm ∥ fill (recE scatter)
    gemmfill_kernel<<<GEMMB + 782, 256, 0, stream>>>(
        xb, Wts[0], hbuf, N_NODES, asrc, adst,
        esrc, edst, ew, rank, ptr, recE);
    msg_main_kernel<<<mb, 256, 0, stream>>>(
        hbuf, asrc, adst, xA, ptr, recE, consts, 0,
        bl[0], gl[0], bel[0], xB, xb);

    // layer 1 (fill branch dead: 782-block grid)
    gemmfill_kernel<<<GEMMB, 256, 0, stream>>>(
        xb, Wts[1], hbuf, N_NODES, asrc, adst,
        esrc, edst, ew, rank, ptr, recE);
    msg_main_kernel<<<mb, 256, 0, stream>>>(
        hbuf, asrc, adst, xB, ptr, recE, consts, 1,
        bl[1], gl[1], bel[1], xA, nullptr);

    pool_kernel<<<(N_NODES + PNODES - 1) / PNODES, 128, 0, stream>>>(xA, batch, pool, gcnt);
    div_kernel<<<(NB * DH + 255) / 256, 256, 0, stream>>>(pool, gcnt, outp);
}

// Round 13
// 342.669 us; speedup vs baseline: 1.1120x; 1.1120x over previous
//
#include <hip/hip_runtime.h>

#define N_NODES 50000
#define N_EDGES 800000
#define DIN 384
#define DH 128
#define NB 64
#define NEG 0.2f

// ---------------- bf16 helpers (exact bit ops) ----------------
__device__ __forceinline__ float bf2f(unsigned short u) {
    return __uint_as_float((unsigned)u << 16);
}
__device__ __forceinline__ unsigned short f2bf(float x) {  // RNE
    unsigned u = __float_as_uint(x);
    return (unsigned short)((u + 0x7fff + ((u >> 16) & 1)) >> 16);
}
__device__ __forceinline__ float sel4(float4 v, int k) {
    float r = v.x;
    r = (k == 1) ? v.y : r;
    r = (k == 2) ? v.z : r;
    r = (k == 3) ? v.w : r;
    return r;
}
using us8 = __attribute__((ext_vector_type(8))) unsigned short;
using short8 = __attribute__((ext_vector_type(8))) short;
using f32x4  = __attribute__((ext_vector_type(4))) float;

// ---------------- tiny Wp transpose+convert (unblocks histproj's us8 staging) ----
__global__ __launch_bounds__(256) void prep_w(const float* __restrict__ Wp,
                                              unsigned short* __restrict__ Wtp)
{
    const int pi = blockIdx.x * 256 + threadIdx.x;   // 0..49151
    const int k = pi >> 7, n = pi & 127;
    Wtp[(size_t)n * DIN + k] = f2bf(Wp[pi]);
}

// ---------------- fused proj GEMM ∥ (histogram + ew-sum) --------------------
// Blocks 0..781: projection GEMM (BM=64), B staged as us8 copies from
// pre-converted Wtp[n][K] (R10-proven: VGPR 40, 2-way b128 bank alias only;
// R12's transposed-write staging was a 16-way conflict — 19.7M SQ_LDS_BANK_CONFLICT).
// Blocks 782..1805: edge histogram grid-stride.
#define PROJB 782
#define HISTB 1024
__global__ __launch_bounds__(256) void histproj_kernel(
    // hist args
    const int* __restrict__ dst, const float* __restrict__ ew,
    int* __restrict__ cnt, int* __restrict__ rank, float* __restrict__ ews,
    // proj args
    const float* __restrict__ A, const unsigned short* __restrict__ Wtp,
    const float* __restrict__ bias, float* __restrict__ C,
    unsigned short* __restrict__ Cb, int M)
{
    const int tid = threadIdx.x;

    if (blockIdx.x >= PROJB) {
        // ---------------- hist ----------------
        __shared__ float sred[4];
        const int hb = blockIdx.x - PROJB;   // 0..1023
        float v = 0.0f;
        for (int i = hb * 256 + tid; i < N_EDGES; i += HISTB * 256) {
            rank[i] = atomicAdd(&cnt[dst[i]], 1);
            v += ew[i];
        }
        #pragma unroll
        for (int o = 32; o; o >>= 1) v += __shfl_down(v, o, 64);
        if ((tid & 63) == 0) sred[tid >> 6] = v;
        __syncthreads();
        if (tid == 0) atomicAdd(ews, sred[0] + sred[1] + sred[2] + sred[3]);
        return;
    }

    // ---------------- projection GEMM (BM=64) ----------------
    constexpr int K = DIN, BM = 64, BK = 32, LS = 40;
    __shared__ unsigned short As[BM * LS];   // 5.1 KB
    __shared__ unsigned short Bs[DH * LS];   // 10.2 KB

    const int w = tid >> 6, l = tid & 63;
    const int lane16 = l & 15, quad = l >> 4;
    const int m0 = blockIdx.x * BM;

    f32x4 acc[8] = {};

    const int ar = tid >> 2, a4 = tid & 3;   // 64 rows x 4 quarters
    int arow = m0 + ar; if (arow >= M) arow = M - 1;
    const float* Ap = A + (size_t)arow * K;

    for (int k0 = 0; k0 < K; k0 += BK) {
        __syncthreads();
        #pragma unroll
        for (int i = 0; i < 2; ++i) {
            const int f4 = a4 + 4 * i;
            float4 v = *(const float4*)(Ap + k0 + f4 * 4);
            ushort4 u = {f2bf(v.x), f2bf(v.y), f2bf(v.z), f2bf(v.w)};
            *(ushort4*)&As[ar * LS + f4 * 4] = u;
        }
        #pragma unroll
        for (int i = 0; i < 2; ++i) {
            const int idx = tid + 256 * i;
            const int bn = idx >> 2, seg = idx & 3;
            us8 v = *(const us8*)(Wtp + (size_t)bn * K + k0 + seg * 8);
            *(us8*)&Bs[bn * LS + seg * 8] = v;
        }
        __syncthreads();
        short8 afr = *(short8*)&As[(w * 16 + lane16) * LS + quad * 8];
        #pragma unroll
        for (int nt = 0; nt < 8; ++nt) {
            short8 bf = *(short8*)&Bs[(nt * 16 + lane16) * LS + quad * 8];
            acc[nt] = __builtin_amdgcn_mfma_f32_16x16x32_bf16(afr, bf, acc[nt], 0, 0, 0);
        }
    }

    const int orow0 = m0 + w * 16 + quad * 4;
    #pragma unroll
    for (int nt = 0; nt < 8; ++nt) {
        const int col = nt * 16 + lane16;
        const float bv = bias[col];
        #pragma unroll
        for (int r = 0; r < 4; ++r) {
            const int row = orow0 + r;
            if (row < M) {
                const float v = acc[nt][r] + bv;
                C[(size_t)row * DH + col] = v;
                Cb[(size_t)row * DH + col] = f2bf(v);
            }
        }
    }
}

// ---------------- scan stage A (+ consts + layer-weight prep) ---------------
#define SB 196
__global__ __launch_bounds__(256) void scan_a(const int* __restrict__ cnt,
                       int* __restrict__ scanned, int* __restrict__ bsums,
                       const float* __restrict__ We0, const float* __restrict__ ae0,
                       const float* __restrict__ We1, const float* __restrict__ ae1,
                       const float* __restrict__ ews, float* __restrict__ consts,
                       const float* __restrict__ W0, const float* __restrict__ W1,
                       const float* __restrict__ as0, const float* __restrict__ ad0,
                       const float* __restrict__ as1, const float* __restrict__ ad1,
                       unsigned short* __restrict__ Wt0, unsigned short* __restrict__ Wt1) {
    __shared__ int s[256];
    const int tid = threadIdx.x;
    if (blockIdx.x < SB) {
        int i = blockIdx.x * 256 + tid;
        int v = (i < N_NODES) ? cnt[i] : 0;
        s[tid] = v; __syncthreads();
        for (int o = 1; o < 256; o <<= 1) {
            int t = (tid >= o) ? s[tid - o] : 0;
            __syncthreads();
            s[tid] += t;
            __syncthreads();
        }
        if (i < N_NODES) scanned[i] = s[tid] - v;  // exclusive
        if (tid == 255) bsums[blockIdx.x] = s[255];
    } else if (blockIdx.x == SB) {
        if (tid < 64) {
            const int l = tid;
            float p00 = We0[l] * ae0[l];
            float p01 = We0[l + 64] * ae0[l + 64];
            float p10 = We1[l] * ae1[l];
            float p11 = We1[l + 64] * ae1[l + 64];
            #pragma unroll
            for (int o = 1; o < 32; o <<= 1) {
                p00 += __shfl_xor(p00, o, 64); p01 += __shfl_xor(p01, o, 64);
                p10 += __shfl_xor(p10, o, 64); p11 += __shfl_xor(p11, o, 64);
            }
            const float c0 = __shfl(p00, 0, 64), c1 = __shfl(p00, 32, 64);
            const float c2 = __shfl(p01, 0, 64), c3 = __shfl(p01, 32, 64);
            const float d0 = __shfl(p10, 0, 64), d1 = __shfl(p10, 32, 64);
            const float d2 = __shfl(p11, 0, 64), d3 = __shfl(p11, 32, 64);
            if (l == 0) {
                consts[0] = c0; consts[1] = c1; consts[2] = c2; consts[3] = c3;
                consts[4] = d0; consts[5] = d1; consts[6] = d2; consts[7] = d3;
                consts[8] = ews[0] * (1.0f / N_EDGES);
            }
        }
    } else if (blockIdx.x <= SB + 64) {
        const int pi = (blockIdx.x - SB - 1) * 256 + tid;  // 0..16383 = DH*DH
        const int k = pi >> 7, n = pi & 127;
        Wt0[(size_t)n * DH + k] = f2bf(W0[pi]);
        Wt1[(size_t)n * DH + k] = f2bf(W1[pi]);
    } else {
        const int b = blockIdx.x - SB - 65;   // 0..3 -> (layer, src/dst)
        const int layer = b >> 1, sd = b & 1;
        const float* Ws = layer ? W1 : W0;
        const float* av = layer ? (sd ? ad1 : as1) : (sd ? ad0 : as0);
        unsigned short* Wt = layer ? Wt1 : Wt0;
        #pragma unroll
        for (int rep = 0; rep < 2; ++rep) {
            const int idx = rep * 256 + tid;   // 0..511 -> (k, hd)
            const int k = idx >> 2, hd = idx & 3;
            float sacc = 0.f;
            for (int f = 0; f < 32; ++f)
                sacc += Ws[k * DH + hd * 32 + f] * av[hd * 32 + f];
            Wt[(size_t)(128 + sd * 4 + hd) * DH + k] = f2bf(sacc);
        }
    }
}

// ---------------- scan stage BC ----------------
__global__ __launch_bounds__(256) void scan_bc(const int* __restrict__ scanned,
                        const int* __restrict__ bsums,
                        const int* __restrict__ cnt, int* __restrict__ ptr) {
    __shared__ int red[4];
    const int tid = threadIdx.x;
    int part = 0;
    for (int j = tid; j < blockIdx.x; j += 256) part += bsums[j];
    #pragma unroll
    for (int o = 32; o; o >>= 1) part += __shfl_down(part, o, 64);
    if ((tid & 63) == 0) red[tid >> 6] = part;
    __syncthreads();
    const int off = red[0] + red[1] + red[2] + red[3];
    const int i = blockIdx.x * 256 + tid;
    if (i < N_NODES) {
        const int p = scanned[i] + off;
        ptr[i] = p;
        if (i == N_NODES - 1) ptr[N_NODES] = p + cnt[i];
    }
}

// ---------------- layer GEMM ∥ fill (layer 0 only) --------------------------
#define GEMMB 782
__global__ __launch_bounds__(256) void gemmfill_kernel(
    const unsigned short* __restrict__ Ab, const unsigned short* __restrict__ Wt,
    unsigned short* __restrict__ Hout, int M,
    float* __restrict__ asrc_o, float* __restrict__ adst_o,
    // fill args
    const int* __restrict__ src, const int* __restrict__ dst,
    const float* __restrict__ ew, const int* __restrict__ rank,
    const int* __restrict__ ptr, int2* __restrict__ recE)
{
    constexpr int K = DH, BM = 64, BK = 32, LS = 40;
    __shared__ unsigned short As[BM * LS];
    __shared__ unsigned short Bs[144 * LS];
    const int tid = threadIdx.x;

    if (blockIdx.x >= GEMMB) {
        const int e0 = ((blockIdx.x - GEMMB) * 256 + tid) * 4;
        if (e0 >= N_EDGES) return;
        const int4 d4 = *(const int4*)(dst + e0);
        const int4 s4 = *(const int4*)(src + e0);
        const int4 r4 = *(const int4*)(rank + e0);
        const float4 w4 = *(const float4*)(ew + e0);
        recE[ptr[d4.x] + r4.x] = make_int2(s4.x, __float_as_int(w4.x));
        recE[ptr[d4.y] + r4.y] = make_int2(s4.y, __float_as_int(w4.y));
        recE[ptr[d4.z] + r4.z] = make_int2(s4.z, __float_as_int(w4.z));
        recE[ptr[d4.w] + r4.w] = make_int2(s4.w, __float_as_int(w4.w));
        return;
    }

    const int w = tid >> 6, l = tid & 63;
    const int lane16 = l & 15, quad = l >> 4;
    const int m0 = blockIdx.x * BM;

    f32x4 acc[9] = {};

    const int ar = tid >> 2, aseg = tid & 3;
    int arow = m0 + ar; if (arow >= M) arow = M - 1;
    const unsigned short* Ap = Ab + (size_t)arow * K;

    for (int k0 = 0; k0 < K; k0 += BK) {
        __syncthreads();
        {
            us8 v = *(const us8*)(Ap + k0 + aseg * 8);
            *(us8*)&As[ar * LS + aseg * 8] = v;
        }
        #pragma unroll
        for (int i = 0; i < 3; ++i) {
            const int idx = tid + 256 * i;
            if (idx < 576) {
                const int bn = idx >> 2, seg = idx & 3;
                us8 v = *(const us8*)(Wt + (size_t)bn * K + k0 + seg * 8);
                *(us8*)&Bs[bn * LS + seg * 8] = v;
            }
        }
        __syncthreads();
        short8 af = *(short8*)&As[(w * 16 + lane16) * LS + quad * 8];
        #pragma unroll
        for (int nt = 0; nt < 9; ++nt) {
            short8 bf = *(short8*)&Bs[(nt * 16 + lane16) * LS + quad * 8];
            acc[nt] = __builtin_amdgcn_mfma_f32_16x16x32_bf16(af, bf, acc[nt], 0, 0, 0);
        }
    }

    const int orow0 = m0 + w * 16 + quad * 4;
    #pragma unroll
    for (int nt = 0; nt < 8; ++nt) {
        const int col = nt * 16 + lane16;
        #pragma unroll
        for (int r = 0; r < 4; ++r) {
            const int row = orow0 + r;
            if (row < M)
                Hout[(size_t)row * DH + col] = f2bf(acc[nt][r]);
        }
    }
    // logits from the 9th tile: cols 0..3 -> asrc, 4..7 -> adst
    #pragma unroll
    for (int r = 0; r < 4; ++r) {
        const int row = orow0 + r;
        if (row < M && lane16 < 8) {
            if (lane16 < 4) asrc_o[(size_t)row * 4 + lane16] = acc[8][r];
            else            adst_o[(size_t)row * 4 + (lane16 - 4)] = acc[8][r];
        }
    }
}

// ---------------- msg node compute (R5 4-edge version; R8 8-edge regressed) --
__device__ __forceinline__ void msg_node(
    const int n, const int c8, const int hd8,
    const float cc_l, const float ewm,
    const unsigned short* __restrict__ h,
    const float* __restrict__ asrc, const float* __restrict__ adst,
    const float* __restrict__ xres,
    const int* __restrict__ indptr, const int2* __restrict__ recE,
    const float* __restrict__ bias, const float* __restrict__ gamma,
    const float* __restrict__ beta, float z[8])
{
    const unsigned short* hb = h + c8 * 8;
    const int st = indptr[n];
    const int deg = indptr[n + 1] - st;
    const float ad_l = adst[(size_t)n * 4 + hd8];
    const float as_l = asrc[(size_t)n * 4 + hd8];

    // self-loop coefficient (|alpha| << 1 -> exp without max-shift is exact softmax)
    float a0 = as_l + ad_l + ewm * cc_l;
    a0 = a0 > 0.f ? a0 : NEG * a0;
    const float pv0_l = __expf(a0);

    float dsum = 0.f;
    float acc8[8];
    {
        us8 u = *(const us8*)(hb + (size_t)n * DH);
        #pragma unroll
        for (int i = 0; i < 8; ++i) acc8[i] = pv0_l * bf2f(u[i]);
    }

    const int2* rq = recE + st;
    int e = 0;
    for (; e + 3 < deg; e += 4) {
        const int2 r0 = rq[e],     r1 = rq[e + 1];
        const int2 r2 = rq[e + 2], r3 = rq[e + 3];
        const float av0 = asrc[(size_t)r0.x * 4 + hd8];
        const float av1 = asrc[(size_t)r1.x * 4 + hd8];
        const float av2 = asrc[(size_t)r2.x * 4 + hd8];
        const float av3 = asrc[(size_t)r3.x * 4 + hd8];
        us8 u0 = *(const us8*)(hb + (size_t)r0.x * DH);
        us8 u1 = *(const us8*)(hb + (size_t)r1.x * DH);
        us8 u2 = *(const us8*)(hb + (size_t)r2.x * DH);
        us8 u3 = *(const us8*)(hb + (size_t)r3.x * DH);
        float al0 = av0 + ad_l + __int_as_float(r0.y) * cc_l;
        float al1 = av1 + ad_l + __int_as_float(r1.y) * cc_l;
        float al2 = av2 + ad_l + __int_as_float(r2.y) * cc_l;
        float al3 = av3 + ad_l + __int_as_float(r3.y) * cc_l;
        al0 = al0 > 0.f ? al0 : NEG * al0;
        al1 = al1 > 0.f ? al1 : NEG * al1;
        al2 = al2 > 0.f ? al2 : NEG * al2;
        al3 = al3 > 0.f ? al3 : NEG * al3;
        const float c0 = __expf(al0), c1 = __expf(al1);
        const float c2 = __expf(al2), c3 = __expf(al3);
        dsum += (c0 + c1) + (c2 + c3);
        #pragma unroll
        for (int i = 0; i < 8; ++i)
            acc8[i] = fmaf(c0, bf2f(u0[i]),
                      fmaf(c1, bf2f(u1[i]),
                      fmaf(c2, bf2f(u2[i]),
                      fmaf(c3, bf2f(u3[i]), acc8[i]))));
    }
    for (; e < deg; ++e) {
        const int2 r = rq[e];
        const float av = asrc[(size_t)r.x * 4 + hd8];
        us8 u = *(const us8*)(hb + (size_t)r.x * DH);
        float al = av + ad_l + __int_as_float(r.y) * cc_l;
        al = al > 0.f ? al : NEG * al;
        const float c = __expf(al);
        dsum += c;
        #pragma unroll
        for (int i = 0; i < 8; ++i) acc8[i] = fmaf(c, bf2f(u[i]), acc8[i]);
    }

    const float inv_d = 1.0f / (dsum + pv0_l + 1e-16f);
    const float4 b4a = *(const float4*)(bias + c8 * 8);
    const float4 b4b = *(const float4*)(bias + c8 * 8 + 4);
    float y[8];
    y[0] = acc8[0] * inv_d + b4a.x; y[1] = acc8[1] * inv_d + b4a.y;
    y[2] = acc8[2] * inv_d + b4a.z; y[3] = acc8[3] * inv_d + b4a.w;
    y[4] = acc8[4] * inv_d + b4b.x; y[5] = acc8[5] * inv_d + b4b.y;
    y[6] = acc8[6] * inv_d + b4b.z; y[7] = acc8[7] * inv_d + b4b.w;

    float s1 = 0.f, s2 = 0.f;
    #pragma unroll
    for (int i = 0; i < 8; ++i) { s1 += y[i]; s2 += y[i] * y[i]; }
    #pragma unroll
    for (int o = 1; o < 16; o <<= 1) {   // stays within the 16-lane group
        s1 += __shfl_xor(s1, o, 64);
        s2 += __shfl_xor(s2, o, 64);
    }
    const float mu = s1 * (1.0f / DH);
    const float var = s2 * (1.0f / DH) - mu * mu;
    const float rs = rsqrtf(var + 1e-5f);

    const float4 g4a = *(const float4*)(gamma + c8 * 8);
    const float4 g4b = *(const float4*)(gamma + c8 * 8 + 4);
    const float4 e4a = *(const float4*)(beta + c8 * 8);
    const float4 e4b = *(const float4*)(beta + c8 * 8 + 4);
    const float4 r4a = *(const float4*)(xres + (size_t)n * DH + c8 * 8);
    const float4 r4b = *(const float4*)(xres + (size_t)n * DH + c8 * 8 + 4);
    const float gv[8] = {g4a.x, g4a.y, g4a.z, g4a.w, g4b.x, g4b.y, g4b.z, g4b.w};
    const float ev[8] = {e4a.x, e4a.y, e4a.z, e4a.w, e4b.x, e4b.y, e4b.z, e4b.w};
    const float rv[8] = {r4a.x, r4a.y, r4a.z, r4a.w, r4b.x, r4b.y, r4b.z, r4b.w};
    #pragma unroll
    for (int i = 0; i < 8; ++i) {
        float t = (y[i] - mu) * rs * gv[i] + ev[i];
        z[i] = (t > 0.f ? t : __expf(t) - 1.0f) + rv[i];
    }
}

// ---------------- msg: full TLP, both layers (pool un-fused per ledger) -----
#define MSG_NPB 16
__global__ __launch_bounds__(256) void msg_main_kernel(
    const unsigned short* __restrict__ h, const float* __restrict__ asrc,
    const float* __restrict__ adst, const float* __restrict__ xres,
    const int* __restrict__ indptr, const int2* __restrict__ recE,
    const float* __restrict__ consts, const int layer,
    const float* __restrict__ bias, const float* __restrict__ gamma,
    const float* __restrict__ beta, float* __restrict__ xout,
    unsigned short* __restrict__ xob)
{
    const int l = threadIdx.x & 63;
    const int wv = threadIdx.x >> 6;
    const int grp = l >> 4, c8 = l & 15, hd8 = c8 >> 2;
    const int n = blockIdx.x * MSG_NPB + wv * 4 + grp;  // exact: 3125*16=50000

    const float cc_l = sel4(*(const float4*)(consts + layer * 4), hd8);
    const float ewm = consts[8];

    float z[8];
    msg_node(n, c8, hd8, cc_l, ewm, h, asrc, adst, xres, indptr, recE,
             bias, gamma, beta, z);

    *(float4*)(xout + (size_t)n * DH + c8 * 8)     = *(float4*)&z[0];
    *(float4*)(xout + (size_t)n * DH + c8 * 8 + 4) = *(float4*)&z[4];
    if (xob) {
        ushort4 ub0 = {f2bf(z[0]), f2bf(z[1]), f2bf(z[2]), f2bf(z[3])};
        ushort4 ub1 = {f2bf(z[4]), f2bf(z[5]), f2bf(z[6]), f2bf(z[7])};
        *(ushort4*)(xob + (size_t)n * DH + c8 * 8)     = ub0;
        *(ushort4*)(xob + (size_t)n * DH + c8 * 8 + 4) = ub1;
    }
}

// ---------------- global mean pool (R3 measured-good structure) -------------
#define PNODES 64
__global__ __launch_bounds__(128) void pool_kernel(const float* __restrict__ x,
        const int* __restrict__ batch, float* __restrict__ pool, int* __restrict__ gcnt)
{
    int t = threadIdx.x;
    int n0 = blockIdx.x * PNODES;
    if (n0 >= N_NODES) return;
    int n1 = min(n0 + PNODES, N_NODES);
    float acc = 0.f; int cn = 0;
    int curb = batch[n0];
    for (int n = n0; n < n1; ++n) {
        int b = batch[n];
        if (b != curb) {
            atomicAdd(&pool[(size_t)curb * DH + t], acc);
            if (t == 0) atomicAdd(&gcnt[curb], cn);
            acc = 0.f; cn = 0; curb = b;
        }
        acc += x[(size_t)n * DH + t];
        ++cn;
    }
    atomicAdd(&pool[(size_t)curb * DH + t], acc);
    if (t == 0) atomicAdd(&gcnt[curb], cn);
}

__global__ void div_kernel(const float* __restrict__ pool, const int* __restrict__ gcnt,
                           float* __restrict__ out)
{
    int i = blockIdx.x * blockDim.x + threadIdx.x;
    if (i < NB * DH) {
        float c = (float)gcnt[i >> 7];
        out[i] = pool[i] / fmaxf(c, 1.0f);
    }
}

// ---------------- launch ----------------
extern "C" void kernel_launch(void* const* d_in, const int* in_sizes, int n_in,
                              void* d_out, int out_size, void* d_ws, size_t ws_size,
                              hipStream_t stream)
{
    const float* nf    = (const float*)d_in[0];
    const int*   esrc  = (const int*)d_in[1];
    const int*   edst  = esrc + N_EDGES;
    const float* ew    = (const float*)d_in[2];
    const int*   batch = (const int*)d_in[3];
    const float* Wp    = (const float*)d_in[4];
    const float* bp    = (const float*)d_in[5];
    const float* Wl[2]  = {(const float*)d_in[6],  (const float*)d_in[14]};
    const float* asl[2] = {(const float*)d_in[7],  (const float*)d_in[15]};
    const float* adl[2] = {(const float*)d_in[8],  (const float*)d_in[16]};
    const float* Wel[2] = {(const float*)d_in[9],  (const float*)d_in[17]};
    const float* ael[2] = {(const float*)d_in[10], (const float*)d_in[18]};
    const float* bl[2]  = {(const float*)d_in[11], (const float*)d_in[19]};
    const float* gl[2]  = {(const float*)d_in[12], (const float*)d_in[20]};
    const float* bel[2] = {(const float*)d_in[13], (const float*)d_in[21]};
    float* outp = (float*)d_out;

    char* w = (char*)d_ws;
    auto alloc = [&](size_t bytes) { char* p = w; w += (bytes + 255) & ~255ull; return p; };
    float* xA     = (float*)alloc((size_t)N_NODES * DH * 4);
    float* xB     = (float*)alloc((size_t)N_NODES * DH * 4);
    unsigned short* hbuf = (unsigned short*)alloc((size_t)N_NODES * DH * 2);
    unsigned short* xb   = (unsigned short*)alloc((size_t)N_NODES * DH * 2);
    float* asrc   = (float*)alloc((size_t)N_NODES * 4 * 4);
    float* adst   = (float*)alloc((size_t)N_NODES * 4 * 4);
    // contiguous zero-init group: pool | gcnt | ews | cnt  (one memset)
    float* pool   = (float*)alloc((size_t)NB * DH * 4);
    int* gcnt     = (int*)alloc(256);
    float* ews    = (float*)alloc(256);
    int* cnt      = (int*)alloc((size_t)N_NODES * 4);
    int* scanned  = (int*)alloc((size_t)N_NODES * 4);
    int* bsums    = (int*)alloc(1024);
    int* ptr      = (int*)alloc((size_t)(N_NODES + 8) * 4);
    int* rank     = (int*)alloc((size_t)N_EDGES * 4);
    int2* recE    = (int2*)alloc((size_t)N_EDGES * 8);
    float* consts = (float*)alloc(256);
    unsigned short* Wtp = (unsigned short*)alloc((size_t)DH * DIN * 2);
    unsigned short* Wt0 = (unsigned short*)alloc((size_t)144 * DH * 2);
    unsigned short* Wt1 = (unsigned short*)alloc((size_t)144 * DH * 2);
    unsigned short* Wts[2] = {Wt0, Wt1};

    hipMemsetAsync(pool, 0, (size_t)NB * DH * 4 + 256 + 256 + (size_t)N_NODES * 4, stream);

    // stage 0: Wp -> Wtp bf16 transpose (tiny; unblocks proj us8 staging)
    prep_w<<<(DIN * DH) / 256, 256, 0, stream>>>(Wp, Wtp);

    // stage 1: proj GEMM ∥ histogram/ew-sum
    histproj_kernel<<<PROJB + HISTB, 256, 0, stream>>>(
        edst, ew, cnt, rank, ews,
        nf, Wtp, bp, xA, xb, N_NODES);

    // stage 2: scan + consts + layer-weight prep (spare blocks)
    scan_a<<<SB + 69, 256, 0, stream>>>(cnt, scanned, bsums,
                                        Wel[0], ael[0], Wel[1], ael[1], ews, consts,
                                        Wl[0], Wl[1], asl[0], adl[0], asl[1], adl[1],
                                        Wt0, Wt1);
    scan_bc<<<SB, 256, 0, stream>>>(scanned, bsums, cnt, ptr);

    const int mb = N_NODES / MSG_NPB;    // 3125

    // layer 0: gemm ∥ fill (recE scatter)
    gemmfill_kernel<<<GEMMB + 782, 256, 0, stream>>>(
        xb, Wts[0], hbuf, N_NODES, asrc, adst,
        esrc, edst, ew, rank, ptr, recE);
    msg_main_kernel<<<mb, 256, 0, stream>>>(
        hbuf, asrc, adst, xA, ptr, recE, consts, 0,
        bl[0], gl[0], bel[0], xB, xb);

    // layer 1 (fill branch dead: 782-block grid)
    gemmfill_kernel<<<GEMMB, 256, 0, stream>>>(
        xb, Wts[1], hbuf, N_NODES, asrc, adst,
        esrc, edst, ew, rank, ptr, recE);
    msg_main_kernel<<<mb, 256, 0, stream>>>(
        hbuf, asrc, adst, xB, ptr, recE, consts, 1,
        bl[1], gl[1], bel[1], xA, nullptr);

    pool_kernel<<<(N_NODES + PNODES - 1) / PNODES, 128, 0, stream>>>(xA, batch, pool, gcnt);
    div_kernel<<<(NB * DH + 255) / 256, 256, 0, stream>>>(pool, gcnt, outp);
}